// Round 1
// baseline (299.128 us; speedup 1.0000x reference)
//
#include <hip/hip_runtime.h>
#include <math.h>

#define BATCH 1024
#define SEQ   200
#define DIN   128
#define DOUT  128
#define HALF  64
#define PSTR  608    // partial-delta row stride (floats): 600 data + 8 pad

typedef __attribute__((ext_vector_type(8))) short short8;
typedef __attribute__((ext_vector_type(4))) float f32x4;

// async global->LDS, 16B per lane; LDS dest = wave-uniform base + lane*16
__device__ __forceinline__ void async_copy16(const void* g, void* l) {
    __builtin_amdgcn_global_load_lds((const __attribute__((address_space(1))) void*)g,
                                     (__attribute__((address_space(3))) void*)l,
                                     16, 0, 0);
}

// fp32 -> packed (bf16_hi << 16) | bf16_lo ; hi = round-half-up, lo = RTZ residual
__device__ __forceinline__ unsigned pack_split(float f) {
    unsigned u = __float_as_uint(f);
    unsigned r = u + 0x8000u;
    unsigned hi = r >> 16;
    float hf = __uint_as_float(r & 0xffff0000u);
    unsigned lo = __float_as_uint(f - hf) >> 16;
    return (hi << 16) | lo;
}

__device__ __forceinline__ void split2(float f, short& h, short& l) {
    unsigned u = __float_as_uint(f);
    unsigned r = u + 0x8000u;
    h = (short)(r >> 16);
    float hf = __uint_as_float(r & 0xffff0000u);
    l = (short)(__float_as_uint(f - hf) >> 16);
}

// exact reconstruction of packed value
__device__ __forceinline__ float unpk(unsigned u) {
    return __uint_as_float(u & 0xffff0000u) + __uint_as_float(u << 16);
}

// ---- pre-split S into MFMA B-fragment order (hi at idx, lo at 16384+idx) ----
__global__ __launch_bounds__(256) void k_presplit(const float* __restrict__ S,
                                                  short* __restrict__ Sp) {
    int g = blockIdx.x * 256 + threadIdx.x;          // 0..16383
    int j = g & 7, lane = (g >> 3) & 63, kt = (g >> 9) & 3, nt = g >> 11;
    int k = kt * 32 + (lane >> 4) * 8 + j;
    int n = nt * 16 + (lane & 15);
    short h, l;
    split2(S[k * DOUT + n], h, l);
    Sp[g] = h;
    Sp[16384 + g] = l;
}

// ---- K1: low_new = A @ S ; 512-thread blocks (8 waves share one Sp stage) ----
// LDS 64 KB, 2 blocks/CU -> 16 waves/CU (was 8). VGPR cap 128 (measured 112).
__global__ __launch_bounds__(512, 4) void k_gemm(const float* __restrict__ A,
                                                 const short* __restrict__ Sp,
                                                 unsigned* __restrict__ outp) {
    __shared__ short sSp[32768];   // 64 KB: hi [0..16383], lo [16384..]
    const int t = threadIdx.x;
    const int w = t >> 6, lane = t & 63;               // w in 0..7
    const int q = lane >> 4, c = lane & 15;
    const long rowb = (long)blockIdx.x * 256 + w * 32;

    // (1) all 16 A-loads issued first (oldest in vmcnt order)
    float4 araw[4][2][2];
#pragma unroll
    for (int kt = 0; kt < 4; ++kt)
#pragma unroll
        for (int mt = 0; mt < 2; ++mt) {
            const float* ap = A + (rowb + mt * 16 + c) * DIN + kt * 32 + q * 8;
            araw[kt][mt][0] = *(const float4*)ap;
            araw[kt][mt][1] = *(const float4*)(ap + 4);
        }

    // (2) async Sp stage: 64 x 1KB chunks, 8 per wave, no VGPR round trip
#pragma unroll
    for (int i = 0; i < 8; ++i) {
        const int g = w * 8 + i;
        async_copy16(Sp + g * 512 + lane * 8, &sSp[g * 512]);
    }

    // (3) split A (waits only on A loads — they retire first)
    short8 ah[4][2], al[4][2];
#pragma unroll
    for (int kt = 0; kt < 4; ++kt)
#pragma unroll
        for (int mt = 0; mt < 2; ++mt) {
            float av[8];
            *(float4*)&av[0] = araw[kt][mt][0];
            *(float4*)&av[4] = araw[kt][mt][1];
#pragma unroll
            for (int j = 0; j < 8; ++j) {
                short h, l;
                split2(av[j], h, l);
                ah[kt][mt][j] = h; al[kt][mt][j] = l;
            }
        }

    f32x4 acc[2][8];
    const f32x4 zz = {0.f, 0.f, 0.f, 0.f};
#pragma unroll
    for (int mt = 0; mt < 2; ++mt)
#pragma unroll
        for (int nt = 0; nt < 8; ++nt) acc[mt][nt] = zz;

    __syncthreads();   // drains async Sp stage

    // (4) MFMA loop: LDS b128 reads (lane-contiguous, conflict-free)
#pragma unroll
    for (int kt = 0; kt < 4; ++kt)
#pragma unroll
        for (int nt = 0; nt < 8; ++nt) {
            const int fo = ((nt * 4 + kt) * 64 + lane) * 8;
            short8 sh = *(const short8*)&sSp[fo];
            short8 sl = *(const short8*)&sSp[16384 + fo];
#pragma unroll
            for (int mt = 0; mt < 2; ++mt) {
                acc[mt][nt] = __builtin_amdgcn_mfma_f32_16x16x32_bf16(ah[kt][mt], sh, acc[mt][nt], 0, 0, 0);
                acc[mt][nt] = __builtin_amdgcn_mfma_f32_16x16x32_bf16(al[kt][mt], sh, acc[mt][nt], 0, 0, 0);
                acc[mt][nt] = __builtin_amdgcn_mfma_f32_16x16x32_bf16(ah[kt][mt], sl, acc[mt][nt], 0, 0, 0);
            }
        }
    // C/D: col = lane&15, row = (lane>>4)*4 + r
#pragma unroll
    for (int mt = 0; mt < 2; ++mt)
#pragma unroll
        for (int nt = 0; nt < 8; ++nt) {
            long r0 = rowb + mt * 16 + q * 4;
#pragma unroll
            for (int r = 0; r < 4; ++r)
                outp[(r0 + r) * DOUT + nt * 16 + c] = pack_split(acc[mt][nt][r]);
        }
}

// ---- K2: one routing iteration; NO LDS staging of low_new (LLC-resident),
//          LDS ~7 KB -> ~6 blocks/CU occupancy. ----
__global__ __launch_bounds__(256, 6) void k_iter(
    const unsigned* __restrict__ lowp,   // [B][200][128] packed hi|lo
    const float* __restrict__ Bm,        // [3][200]
    const int* __restrict__ seq,         // [B]
    const float* __restrict__ acc0, const float* __restrict__ acc1,
    float* __restrict__ part,            // [2048][PSTR]
    float* __restrict__ out, int iter) {
    __shared__ float sW[SEQ * 4];          // [l][k], k<3 used (3.2 KB)
    __shared__ float pB[4][3][HALF];       // per-wave Pass-B partials (3 KB)
    __shared__ float sH[3][HALF];          // squashed high (0.75 KB)

    const int t = threadIdx.x;
    const int lane = t & 63, w = t >> 6;
    const int b = blockIdx.x >> 1, half = blockIdx.x & 1;
    const unsigned* lp = lowp + (size_t)b * (SEQ * DIN) + half * HALF;
    const int n = seq[b];

    // (1) softmax over logits (waves 0..2, one k each)
    if (w < 3) {
        const int k = w;
        float vv[4], m = -INFINITY;
#pragma unroll
        for (int i = 0; i < 4; ++i) {
            int l = lane + 64 * i;
            bool inb = (l < SEQ);
            float v = inb ? Bm[k * SEQ + l] : 0.f;
            if (iter >= 1 && inb) v += acc0[k * SEQ + l];
            if (iter >= 2 && inb) v += acc1[k * SEQ + l];
            vv[i] = (l < n) ? v : -INFINITY;   // l<n implies l<SEQ
            if (l < n) m = fmaxf(m, v);
        }
        for (int off = 32; off; off >>= 1) m = fmaxf(m, __shfl_xor(m, off, 64));
        float s = 0.f, pv[4];
#pragma unroll
        for (int i = 0; i < 4; ++i) {
            pv[i] = (vv[i] == -INFINITY) ? 0.f : expf(vv[i] - m);
            s += pv[i];
        }
        for (int off = 32; off; off >>= 1) s += __shfl_xor(s, off, 64);
        float rs = 1.f / s;
#pragma unroll
        for (int i = 0; i < 4; ++i) {
            int l = lane + 64 * i;
            if (l < SEQ) sW[l * 4 + k] = pv[i] * rs;
        }
    }
    __syncthreads();

    // (2) Pass B: H = W @ low_new. wave w sums l in [50w, 50w+50); lane = e.
    //     Global reads, coalesced 256B/wave-inst, L2/LLC-resident.
    {
        const int e = lane;
        const unsigned* col = lp + e;
        float h0 = 0.f, h1 = 0.f, h2 = 0.f;
#pragma unroll 10
        for (int i = 0; i < 50; ++i) {
            int l = w * 50 + i;
            float4 wv = *(const float4*)&sW[l * 4];   // wave-uniform broadcast
            float f = unpk(col[(size_t)l * DIN]);
            h0 = fmaf(wv.x, f, h0);
            h1 = fmaf(wv.y, f, h1);
            h2 = fmaf(wv.z, f, h2);
        }
        pB[w][0][e] = h0; pB[w][1][e] = h1; pB[w][2][e] = h2;
    }
    __syncthreads();

    // (3) cross-wave reduce + squash (single wave)
    if (t < HALF) {
        float g0 = pB[0][0][t] + pB[1][0][t] + pB[2][0][t] + pB[3][0][t];
        float g1 = pB[0][1][t] + pB[1][1][t] + pB[2][1][t] + pB[3][1][t];
        float g2 = pB[0][2][t] + pB[1][2][t] + pB[2][2][t] + pB[3][2][t];
        float sq = g0 * g0 + g1 * g1 + g2 * g2;
        float scale = sq / (1.f + sq) / sqrtf(sq + 1e-9f);
        g0 *= scale; g1 *= scale; g2 *= scale;
        if (iter == 2) {
            size_t o = (size_t)b * 3 * DOUT + half * HALF + t;
            out[o] = g0; out[o + DOUT] = g1; out[o + 2 * DOUT] = g2;
        } else {
            sH[0][t] = g0; sH[1][t] = g1; sH[2][t] = g2;
        }
    }
    if (iter == 2) return;   // uniform exit
    __syncthreads();

    // (4) Pass C: B_delta partials; thread = l, reads its own row (16B/lane
    //     gathers, L2-resident). sH reads are wave-uniform broadcasts.
    if (t < SEQ) {
        const int l = t;
        const unsigned* row = lp + (size_t)l * DIN;
        float d0 = 0.f, d1 = 0.f, d2 = 0.f;
#pragma unroll
        for (int j = 0; j < 16; ++j) {
            uint4 u = *(const uint4*)&row[4 * j];
            float4 x0 = *(const float4*)&sH[0][4 * j];
            float4 x1 = *(const float4*)&sH[1][4 * j];
            float4 x2 = *(const float4*)&sH[2][4 * j];
            float f0 = unpk(u.x), f1 = unpk(u.y), f2 = unpk(u.z), f3 = unpk(u.w);
            d0 += x0.x * f0 + x0.y * f1 + x0.z * f2 + x0.w * f3;
            d1 += x1.x * f0 + x1.y * f1 + x1.z * f2 + x1.w * f3;
            d2 += x2.x * f0 + x2.y * f1 + x2.z * f2 + x2.w * f3;
        }
        float* pp = part + (size_t)blockIdx.x * PSTR;
        pp[l] = d0;
        pp[SEQ + l] = d1;
        pp[2 * SEQ + l] = d2;
    }
}

// ---- K3: column-sum part[2048][PSTR] -> accN[600]; 150 blocks x 4 cols ----
__global__ __launch_bounds__(256) void k_reduce(const float* __restrict__ part,
                                                float* __restrict__ accN) {
    __shared__ float sP[4][4];
    const int t = threadIdx.x, lane = t & 63, w = t >> 6;
    const int c4 = blockIdx.x * 4;
    float sx = 0.f, sy = 0.f, sz = 0.f, sw = 0.f;
#pragma unroll
    for (int i = 0; i < 8; ++i) {
        float4 v = *(const float4*)&part[(size_t)(t + 256 * i) * PSTR + c4];
        sx += v.x; sy += v.y; sz += v.z; sw += v.w;
    }
#pragma unroll
    for (int off = 1; off < 64; off <<= 1) {
        sx += __shfl_xor(sx, off, 64);
        sy += __shfl_xor(sy, off, 64);
        sz += __shfl_xor(sz, off, 64);
        sw += __shfl_xor(sw, off, 64);
    }
    if (lane == 0) { sP[w][0] = sx; sP[w][1] = sy; sP[w][2] = sz; sP[w][3] = sw; }
    __syncthreads();
    if (t < 4)
        accN[c4 + t] = sP[0][t] + sP[1][t] + sP[2][t] + sP[3][t];
}

extern "C" void kernel_launch(void* const* d_in, const int* in_sizes, int n_in,
                              void* d_out, int out_size, void* d_ws, size_t ws_size,
                              hipStream_t stream) {
    const float* low_capsule = (const float*)d_in[0];   // [1024][200][128]
    const float* B_matrix    = (const float*)d_in[1];   // [1][3][200]
    const float* S_matrix    = (const float*)d_in[2];   // [128][128]
    const int*   seq_len     = (const int*)d_in[3];     // [1024]
    float* out = (float*)d_out;                         // [1024][3][128]

    unsigned* lowp = (unsigned*)d_ws;                              // 26,214,400 u32
    short* Sp      = (short*)(lowp + (size_t)BATCH * SEQ * DOUT);  // 32768 shorts
    float* acc0    = (float*)(Sp + 32768);                         // 600
    float* acc1    = acc0 + 640;                                   // 600
    float* part    = acc1 + 640;                                   // 2048 * PSTR

    k_presplit<<<64, 256, 0, stream>>>(S_matrix, Sp);
    k_gemm<<<(BATCH * SEQ) / 256, 512, 0, stream>>>(low_capsule, Sp, lowp);

    k_iter<<<2 * BATCH, 256, 0, stream>>>(lowp, B_matrix, seq_len, acc0, acc1, part, out, 0);
    k_reduce<<<150, 256, 0, stream>>>(part, acc0);
    k_iter<<<2 * BATCH, 256, 0, stream>>>(lowp, B_matrix, seq_len, acc0, acc1, part, out, 1);
    k_reduce<<<150, 256, 0, stream>>>(part, acc1);
    k_iter<<<2 * BATCH, 256, 0, stream>>>(lowp, B_matrix, seq_len, acc0, acc1, part, out, 2);
}